// Round 2
// baseline (261.765 us; speedup 1.0000x reference)
//
#include <hip/hip_runtime.h>

// Output layout: (B=512, H=128, W=128, C=5), float32.
// ch0 = stamp[h,w]; ch1 = scatter-add (separate kernel); ch2 = x[b, h>>2];
// ch3 = |x[b,h>>2]-x[b,w>>2]| / (max_b - min_b); ch4 = bar chart.
// Static bar layout for D=32,W=128: bar_w=1, gap=2, beg=15 -> col 17+3i is bar i (i in 0..31).

__global__ __launch_bounds__(256) void di_main(const float* __restrict__ inputs,
                                               const float* __restrict__ stamp,
                                               float* __restrict__ out) {
    const int blk = blockIdx.x;     // 8192 blocks: 512 b x 16 slices
    const int b = blk >> 4;
    const int part = blk & 15;
    const int tid = threadIdx.x;

    __shared__ float xs[32];
    __shared__ int bh[32];
    if (tid < 32) {
        float v = inputs[b * 32 + tid];
        xs[tid] = v;
        int t = (int)rintf(v * 128.0f);   // round-half-to-even, matches np.round
        bh[tid] = t < 0 ? 0 : (t > 128 ? 128 : t);
    }
    __syncthreads();

    float mn = xs[0], mx = xs[0];
#pragma unroll
    for (int d = 1; d < 32; ++d) {
        float v = xs[d];
        mn = fminf(mn, v);
        mx = fmaxf(mx, v);
    }
    const float inv = 1.0f / (mx - mn);   // dm min is 0 (diagonal), max is mx-mn

    // 4 consecutive pixels per thread = 20 floats = 80B contiguous
    const int lp = part * 1024 + tid * 4;   // pixel index within this image
    const int h = lp >> 7;
    const int w0 = lp & 127;                // multiple of 4 -> one col-group

    const float rowv = xs[h >> 2];
    const float ndv = fabsf(rowv - xs[w0 >> 2]) * inv;

    const float4 sv = *reinterpret_cast<const float4*>(stamp + h * 128 + w0);
    const float svj[4] = {sv.x, sv.y, sv.z, sv.w};

    alignas(16) float vals[20];
#pragma unroll
    for (int j = 0; j < 4; ++j) {
        const int w = w0 + j;
        float barv = 0.0f;
        const int t = w - 17;
        if (t >= 0 && t <= 93 && (t % 3) == 0) {
            const int bar = t / 3;
            barv = (h < bh[bar]) ? 1.0f : 0.0f;
        }
        vals[5 * j + 0] = svj[j];
        vals[5 * j + 1] = 0.0f;             // ch1 filled by scatter kernel
        vals[5 * j + 2] = rowv;
        vals[5 * j + 3] = ndv;
        vals[5 * j + 4] = barv;
    }

    float4* dst = reinterpret_cast<float4*>(out + ((size_t)b * 16384 + (size_t)lp) * 5);
    const float4* src = reinterpret_cast<const float4*>(vals);
#pragma unroll
    for (int k = 0; k < 5; ++k) dst[k] = src[k];    // 80B contiguous per lane
}

// One thread per b. Exact duplicate handling: for the first occurrence of each
// (r,c) pair, sum all matching inputs in fp32 (matches scatter_nd add), write once.
__global__ void di_scatter(const float* __restrict__ inputs,
                           const int* __restrict__ coords,
                           float* __restrict__ out) {
    const int b = blockIdx.x * blockDim.x + threadIdx.x;
    if (b >= 512) return;
    const float* xb = inputs + b * 32;
    for (int d = 0; d < 32; ++d) {
        const int r = coords[2 * d], c = coords[2 * d + 1];
        bool first = true;
        for (int e = 0; e < d; ++e)
            if (coords[2 * e] == r && coords[2 * e + 1] == c) { first = false; break; }
        if (!first) continue;
        float s = 0.0f;
        for (int e = d; e < 32; ++e)
            if (coords[2 * e] == r && coords[2 * e + 1] == c) s += xb[e];
        out[(((size_t)b * 128 + r) * 128 + c) * 5 + 1] = s;
    }
}

extern "C" void kernel_launch(void* const* d_in, const int* in_sizes, int n_in,
                              void* d_out, int out_size, void* d_ws, size_t ws_size,
                              hipStream_t stream) {
    const float* inputs = (const float*)d_in[0];   // [512,32]
    const float* stamp  = (const float*)d_in[1];   // [128,128,1]
    const int*   coords = (const int*)d_in[2];     // [32,2]
    float* out = (float*)d_out;                    // [512,128,128,5]

    di_main<<<8192, 256, 0, stream>>>(inputs, stamp, out);
    di_scatter<<<2, 256, 0, stream>>>(inputs, coords, out);
}

// Round 3
// 169.594 us; speedup vs baseline: 1.5435x; 1.5435x over previous
//
#include <hip/hip_runtime.h>

// Output layout: (B=512, H=128, W=128, C=5), float32.
// ch0 = stamp[h,w]; ch1 = scatter-add (atomic kernel); ch2 = x[b, h>>2];
// ch3 = |x[b,h>>2]-x[b,w>>2]| / (max_b - min_b); ch4 = bar chart.
// Static bar layout for D=32,W=128: bar_w=1, gap=2, beg=15 -> col 17+3i is bar i (i in 0..31).

__global__ __launch_bounds__(256) void di_main(const float* __restrict__ inputs,
                                               const float* __restrict__ stamp,
                                               float* __restrict__ out) {
    const int blk = blockIdx.x;     // 8192 blocks: 512 b x 16 slices
    const int b = blk >> 4;
    const int part = blk & 15;
    const int tid = threadIdx.x;

    __shared__ float xs[32];
    __shared__ int bh[32];
    __shared__ float buf[256 * 20];   // 20 KB staging for coalesced writes

    if (tid < 32) {
        float v = inputs[b * 32 + tid];
        xs[tid] = v;
        int t = (int)rintf(v * 128.0f);   // round-half-to-even, matches np.round
        bh[tid] = t < 0 ? 0 : (t > 128 ? 128 : t);
    }
    __syncthreads();

    float mn = xs[0], mx = xs[0];
#pragma unroll
    for (int d = 1; d < 32; ++d) {
        float v = xs[d];
        mn = fminf(mn, v);
        mx = fmaxf(mx, v);
    }
    const float inv = 1.0f / (mx - mn);   // dm min is 0 (diagonal), max is mx-mn

    // 4 consecutive pixels per thread = 20 floats
    const int lp = part * 1024 + tid * 4;   // pixel index within this image
    const int h = lp >> 7;
    const int w0 = lp & 127;                // multiple of 4 -> one col-group

    const float rowv = xs[h >> 2];
    const float ndv = fabsf(rowv - xs[w0 >> 2]) * inv;

    const float4 sv = *reinterpret_cast<const float4*>(stamp + h * 128 + w0);
    const float svj[4] = {sv.x, sv.y, sv.z, sv.w};

    alignas(16) float vals[20];
#pragma unroll
    for (int j = 0; j < 4; ++j) {
        const int w = w0 + j;
        float barv = 0.0f;
        const int t = w - 17;
        if (t >= 0 && t <= 93 && (t % 3) == 0) {
            const int bar = t / 3;
            barv = (h < bh[bar]) ? 1.0f : 0.0f;
        }
        vals[5 * j + 0] = svj[j];
        vals[5 * j + 1] = 0.0f;             // ch1 filled by scatter kernel
        vals[5 * j + 2] = rowv;
        vals[5 * j + 3] = ndv;
        vals[5 * j + 4] = barv;
    }

    // stage into LDS (word base tid*20, 16B-aligned; odd float4 stride = baseline b128 banking)
    float4* lw = reinterpret_cast<float4*>(&buf[tid * 20]);
    const float4* src = reinterpret_cast<const float4*>(vals);
#pragma unroll
    for (int k = 0; k < 5; ++k) lw[k] = src[k];
    __syncthreads();

    // stream out: stride-1 float4 per lane -> each wave store = contiguous 1024B
    float4* dst = reinterpret_cast<float4*>(out + ((size_t)b * 16384 + (size_t)part * 1024) * 5);
    const float4* lr = reinterpret_cast<const float4*>(buf);
#pragma unroll
    for (int it = 0; it < 5; ++it) {
        const int f = it * 256 + tid;
        dst[f] = lr[f];
    }
}

// One thread per (b,d): atomicAdd into ch1 (zeroed by di_main; same-stream order).
// Duplicate (r,c) within a b sum via the atomic, matching scatter_nd add.
__global__ __launch_bounds__(256) void di_scatter(const float* __restrict__ inputs,
                                                  const int* __restrict__ coords,
                                                  float* __restrict__ out) {
    const int i = blockIdx.x * blockDim.x + threadIdx.x;
    if (i >= 512 * 32) return;
    const int b = i >> 5;
    const int d = i & 31;
    const int r = coords[2 * d], c = coords[2 * d + 1];
    atomicAdd(&out[(((size_t)b * 128 + r) * 128 + c) * 5 + 1], inputs[i]);
}

extern "C" void kernel_launch(void* const* d_in, const int* in_sizes, int n_in,
                              void* d_out, int out_size, void* d_ws, size_t ws_size,
                              hipStream_t stream) {
    const float* inputs = (const float*)d_in[0];   // [512,32]
    const float* stamp  = (const float*)d_in[1];   // [128,128,1]
    const int*   coords = (const int*)d_in[2];     // [32,2]
    float* out = (float*)d_out;                    // [512,128,128,5]

    di_main<<<8192, 256, 0, stream>>>(inputs, stamp, out);
    di_scatter<<<64, 256, 0, stream>>>(inputs, coords, out);
}

// Round 4
// 167.698 us; speedup vs baseline: 1.5609x; 1.0113x over previous
//
#include <hip/hip_runtime.h>

// Output layout: (B=512, H=128, W=128, C=5), float32.
// ch0 = stamp[h,w]; ch1 = scatter-add (fused, LDS atomics); ch2 = x[b, h>>2];
// ch3 = |x[b,h>>2]-x[b,w>>2]| / (max_b - min_b); ch4 = bar chart.
// Static bar layout for D=32,W=128: bar_w=1, gap=2, beg=15 -> col 17+3i is bar i (i in 0..31).
// Block = (b, part): 1024 pixels = rows part*8 .. part*8+7 of image b.

__global__ __launch_bounds__(256) void di_main(const float* __restrict__ inputs,
                                               const float* __restrict__ stamp,
                                               const int* __restrict__ coords,
                                               float* __restrict__ out) {
    const int blk = blockIdx.x;     // 8192 blocks: 512 b x 16 slices
    const int b = blk >> 4;
    const int part = blk & 15;
    const int tid = threadIdx.x;

    __shared__ float xs[32];
    __shared__ int bh[32];
    __shared__ float sinv;
    __shared__ float buf[256 * 20];   // 20 KB staging for coalesced writes

    // ---- preamble: wave 0 loads x, computes bar heights and 1/(max-min) ----
    if (tid < 64) {
        float v = inputs[b * 32 + (tid & 31)];    // lanes 32..63 duplicate -> min/max unchanged
        if (tid < 32) {
            xs[tid] = v;
            int t = (int)rintf(v * 128.0f);       // round-half-to-even, matches np.round
            bh[tid] = t < 0 ? 0 : (t > 128 ? 128 : t);
        }
        float mn = v, mx = v;
#pragma unroll
        for (int off = 1; off < 32; off <<= 1) {
            mn = fminf(mn, __shfl_xor(mn, off));
            mx = fmaxf(mx, __shfl_xor(mx, off));
        }
        if (tid == 0) sinv = 1.0f / (mx - mn);    // dm min is 0 (diagonal), max is mx-mn
    }
    __syncthreads();

    const float inv = sinv;

    // ---- compute 4 consecutive pixels = 20 floats ----
    const int lp = part * 1024 + tid * 4;   // pixel index within this image
    const int h = lp >> 7;
    const int w0 = lp & 127;                // multiple of 4 -> one col-group

    const float rowv = xs[h >> 2];
    const float ndv = fabsf(rowv - xs[w0 >> 2]) * inv;

    const float4 sv = *reinterpret_cast<const float4*>(stamp + h * 128 + w0);
    const float svj[4] = {sv.x, sv.y, sv.z, sv.w};

    alignas(16) float vals[20];
#pragma unroll
    for (int j = 0; j < 4; ++j) {
        const int w = w0 + j;
        float barv = 0.0f;
        const int t = w - 17;
        if (t >= 0 && t <= 93 && (t % 3) == 0) {
            const int bar = t / 3;
            barv = (h < bh[bar]) ? 1.0f : 0.0f;
        }
        vals[5 * j + 0] = svj[j];
        vals[5 * j + 1] = 0.0f;             // ch1: scatter added below
        vals[5 * j + 2] = rowv;
        vals[5 * j + 3] = ndv;
        vals[5 * j + 4] = barv;
    }

    // stage into LDS (word base tid*20; odd float4 stride = baseline b128 banking)
    float4* lw = reinterpret_cast<float4*>(&buf[tid * 20]);
    const float4* src = reinterpret_cast<const float4*>(vals);
#pragma unroll
    for (int k = 0; k < 5; ++k) lw[k] = src[k];
    __syncthreads();

    // ---- fused scatter: coord d lands in this block iff r>>3 == part ----
    if (tid < 32) {
        const int r = coords[2 * tid], c = coords[2 * tid + 1];
        if ((r >> 3) == part)
            atomicAdd(&buf[((r & 7) * 128 + c) * 5 + 1], xs[tid]);  // duplicates sum via atomic
    }
    __syncthreads();

    // ---- stream out: stride-1 float4 per lane -> each wave store = contiguous 1024B ----
    float4* dst = reinterpret_cast<float4*>(out + ((size_t)b * 16384 + (size_t)part * 1024) * 5);
    const float4* lr = reinterpret_cast<const float4*>(buf);
#pragma unroll
    for (int it = 0; it < 5; ++it) {
        const int f = it * 256 + tid;
        dst[f] = lr[f];
    }
}

extern "C" void kernel_launch(void* const* d_in, const int* in_sizes, int n_in,
                              void* d_out, int out_size, void* d_ws, size_t ws_size,
                              hipStream_t stream) {
    const float* inputs = (const float*)d_in[0];   // [512,32]
    const float* stamp  = (const float*)d_in[1];   // [128,128,1]
    const int*   coords = (const int*)d_in[2];     // [32,2]
    float* out = (float*)d_out;                    // [512,128,128,5]

    di_main<<<8192, 256, 0, stream>>>(inputs, stamp, coords, out);
}